// Round 1
// baseline (2598.732 us; speedup 1.0000x reference)
//
#include <hip/hip_runtime.h>
#include <math.h>

#define N_NODES 50000
#define N_EDGES 800000
#define F_IN    128
#define HID     64
#define HEADS   4
#define HC      256      // HEADS*HID
#define EDIM    9

__device__ inline void atomicMaxFloat(float* addr, float val) {
    if (val >= 0.f) atomicMax((int*)addr, __float_as_int(val));
    else            atomicMin((unsigned int*)addr, __float_as_uint(val));
}

// One block (256 thr) per node: xl = in@Wl+bl, xr = in@Wr+br (K = 128 or 64).
// Also inits per-node softmax state and hnew accumulator for this layer.
__global__ void node_transform(const float* __restrict__ in, int K, int act,
                               const float* __restrict__ Wl, const float* __restrict__ bl,
                               const float* __restrict__ Wr, const float* __restrict__ br,
                               float* __restrict__ xl, float* __restrict__ xr,
                               float* __restrict__ mx, float* __restrict__ dnm,
                               float* __restrict__ hnew) {
    __shared__ float s_in[F_IN];
    const int node = blockIdx.x;
    const int t = threadIdx.x;
    if (t < K) {
        float v = in[(size_t)node * K + t];
        if (act) v = v >= 0.f ? v : 0.01f * v;
        s_in[t] = v;
    }
    if (t < HEADS) {
        mx[node * HEADS + t]  = -INFINITY;
        dnm[node * HEADS + t] = 0.f;
    }
    if (t < HID) hnew[(size_t)node * HID + t] = 0.f;
    __syncthreads();
    float accl = bl[t], accr = br[t];
    for (int k = 0; k < K; ++k) {
        float v = s_in[k];
        accl = fmaf(v, Wl[k * HC + t], accl);
        accr = fmaf(v, Wr[k * HC + t], accr);
    }
    xl[(size_t)node * HC + t] = accl;
    xr[(size_t)node * HC + t] = accr;
}

// One wave (64 lanes) per edge; lane handles 4 channels (float4).
// logits[e][h] = sum_c leaky02(xl[s]+xr[d]+ea@We)[h][c] * att[h][c]
__global__ void edge_logits(const float* __restrict__ ea,
                            const int* __restrict__ src, const int* __restrict__ dst,
                            const float* __restrict__ We, const float* __restrict__ att,
                            const float* __restrict__ xl, const float* __restrict__ xr,
                            float* __restrict__ plog, float* __restrict__ mx) {
    const int wave = threadIdx.x >> 6;
    const int lane = threadIdx.x & 63;
    const int e = blockIdx.x * 4 + wave;
    if (e >= N_EDGES) return;
    const int s = src[e], d = dst[e];

    float ef[EDIM];
    #pragma unroll
    for (int j = 0; j < EDIM; ++j) ef[j] = ea[(size_t)e * EDIM + j];

    const int c0 = lane * 4;
    const float4 vxl = *(const float4*)(xl + (size_t)s * HC + c0);
    const float4 vxr = *(const float4*)(xr + (size_t)d * HC + c0);
    const float4 vat = *(const float4*)(att + c0);
    float partial = 0.f;
    #pragma unroll
    for (int u = 0; u < 4; ++u) {
        const int c = c0 + u;
        float ev = 0.f;
        #pragma unroll
        for (int j = 0; j < EDIM; ++j) ev = fmaf(ef[j], We[j * HC + c], ev);
        float m = (&vxl.x)[u] + (&vxr.x)[u] + ev;
        m = m >= 0.f ? m : 0.2f * m;
        partial = fmaf(m, (&vat.x)[u], partial);
    }
    // reduce 16 lanes -> head logit (lanes 16h..16h+15 hold head h)
    partial += __shfl_down(partial, 8, 64);
    partial += __shfl_down(partial, 4, 64);
    partial += __shfl_down(partial, 2, 64);
    partial += __shfl_down(partial, 1, 64);
    if ((lane & 15) == 0) {
        const int hh = lane >> 4;
        plog[(size_t)e * HEADS + hh] = partial;
        atomicMaxFloat(&mx[d * HEADS + hh], partial);
    }
}

// thread per (edge, head): p = exp(logit - mx[dst]); denom += p
__global__ void edge_softmax_denom(const int* __restrict__ dst,
                                   float* __restrict__ plog,
                                   const float* __restrict__ mx,
                                   float* __restrict__ dnm) {
    const int i = blockIdx.x * blockDim.x + threadIdx.x;
    if (i >= N_EDGES * HEADS) return;
    const int e = i >> 2, hh = i & 3;
    const int d = dst[e];
    const float p = expf(plog[i] - mx[d * HEADS + hh]);
    plog[i] = p;
    atomicAdd(&dnm[d * HEADS + hh], p);
}

// One wave per edge; lane c in [0,64): hnew[d][c] += sum_h 0.25*alpha_h*xl[s][h*64+c]
__global__ void edge_scatter(const int* __restrict__ src, const int* __restrict__ dst,
                             const float* __restrict__ xl, const float* __restrict__ plog,
                             const float* __restrict__ dnm, float* __restrict__ hnew) {
    const int wave = threadIdx.x >> 6;
    const int lane = threadIdx.x & 63;
    const int e = blockIdx.x * 4 + wave;
    if (e >= N_EDGES) return;
    const int s = src[e], d = dst[e];
    float w[HEADS];
    #pragma unroll
    for (int hh = 0; hh < HEADS; ++hh)
        w[hh] = 0.25f * plog[(size_t)e * HEADS + hh] / (dnm[d * HEADS + hh] + 1e-16f);
    float val = 0.f;
    #pragma unroll
    for (int hh = 0; hh < HEADS; ++hh)
        val = fmaf(w[hh], xl[(size_t)s * HC + hh * HID + lane], val);
    atomicAdd(&hnew[(size_t)d * HID + lane], val);
}

// per (node, channel): bias + (optionally) sigmoid-gated residual
__global__ void finalize(const float* __restrict__ hnew, const float* __restrict__ bias,
                         const float* __restrict__ gates, float* __restrict__ h,
                         int gated, int gate_idx) {
    const int i = blockIdx.x * blockDim.x + threadIdx.x;
    if (i >= N_NODES * HID) return;
    const int c = i & (HID - 1);
    float v = hnew[i] + bias[c];
    if (gated) {
        const float g = 1.f / (1.f + expf(-gates[gate_idx]));
        float a = h[i];
        a = a >= 0.f ? a : 0.01f * a;
        v = g * v + (1.f - g) * a;
    }
    h[i] = v;
}

extern "C" void kernel_launch(void* const* d_in, const int* in_sizes, int n_in,
                              void* d_out, int out_size, void* d_ws, size_t ws_size,
                              hipStream_t stream) {
    const float* x     = (const float*)d_in[0];
    const float* ea    = (const float*)d_in[1];
    const float* iWl   = (const float*)d_in[2];
    const float* ibl   = (const float*)d_in[3];
    const float* iWr   = (const float*)d_in[4];
    const float* ibr   = (const float*)d_in[5];
    const float* iWe   = (const float*)d_in[6];
    const float* iatt  = (const float*)d_in[7];
    const float* ibias = (const float*)d_in[8];
    const float* Wl    = (const float*)d_in[9];
    const float* bl    = (const float*)d_in[10];
    const float* Wr    = (const float*)d_in[11];
    const float* br    = (const float*)d_in[12];
    const float* We    = (const float*)d_in[13];
    const float* att   = (const float*)d_in[14];
    const float* bias  = (const float*)d_in[15];
    const float* gates = (const float*)d_in[16];
    const int*   ei    = (const int*)d_in[17];
    const int* src = ei;
    const int* dst = ei + N_EDGES;

    float* ws   = (float*)d_ws;
    float* xl   = ws;
    float* xr   = xl   + (size_t)N_NODES * HC;
    float* plog = xr   + (size_t)N_NODES * HC;
    float* mx   = plog + (size_t)N_EDGES * HEADS;
    float* dnm  = mx   + (size_t)N_NODES * HEADS;
    float* hnew = dnm  + (size_t)N_NODES * HEADS;
    float* h    = (float*)d_out;

    for (int layer = 0; layer < 3; ++layer) {
        const float* in_   = (layer == 0) ? x : h;
        const int    K     = (layer == 0) ? F_IN : HID;
        const int    act   = (layer == 0) ? 0 : 1;
        const float* wl_   = (layer == 0) ? iWl   : Wl   + (size_t)(layer - 1) * HID * HC;
        const float* bl_   = (layer == 0) ? ibl   : bl   + (size_t)(layer - 1) * HC;
        const float* wr_   = (layer == 0) ? iWr   : Wr   + (size_t)(layer - 1) * HID * HC;
        const float* br_   = (layer == 0) ? ibr   : br   + (size_t)(layer - 1) * HC;
        const float* we_   = (layer == 0) ? iWe   : We   + (size_t)(layer - 1) * EDIM * HC;
        const float* att_  = (layer == 0) ? iatt  : att  + (size_t)(layer - 1) * HC;
        const float* bias_ = (layer == 0) ? ibias : bias + (size_t)(layer - 1) * HID;

        node_transform<<<N_NODES, 256, 0, stream>>>(in_, K, act, wl_, bl_, wr_, br_,
                                                    xl, xr, mx, dnm, hnew);
        edge_logits<<<N_EDGES / 4, 256, 0, stream>>>(ea, src, dst, we_, att_, xl, xr, plog, mx);
        edge_softmax_denom<<<(N_EDGES * HEADS + 255) / 256, 256, 0, stream>>>(dst, plog, mx, dnm);
        edge_scatter<<<N_EDGES / 4, 256, 0, stream>>>(src, dst, xl, plog, dnm, hnew);
        finalize<<<(N_NODES * HID + 255) / 256, 256, 0, stream>>>(hnew, bias_, gates, h,
                                                                  (layer == 0) ? 0 : 1, layer - 1);
    }
}

// Round 2
// 2008.594 us; speedup vs baseline: 1.2938x; 1.2938x over previous
//
#include <hip/hip_runtime.h>
#include <math.h>

#define N_NODES 50000
#define N_EDGES 800000
#define F_IN    128
#define HID     64
#define HEADS   4
#define HC      256      // HEADS*HID
#define EDIM    9
#define MB      16       // nodes per block in node_transform (50000/16 = 3125 exact)

__device__ inline void atomicMaxFloat(float* addr, float val) {
    if (val >= 0.f) atomicMax((int*)addr, __float_as_int(val));
    else            atomicMin((unsigned int*)addr, __float_as_uint(val));
}

// 256 threads, MB nodes per block. Each thread owns one output column t of HC.
// Weights read once per 16 nodes (16x less L2 traffic); x tile staged in LDS.
__global__ void node_transform(const float* __restrict__ in, int K, int act,
                               const float* __restrict__ Wl, const float* __restrict__ bl,
                               const float* __restrict__ Wr, const float* __restrict__ br,
                               float* __restrict__ xl, float* __restrict__ xr,
                               float* __restrict__ mx, float* __restrict__ dnm,
                               float* __restrict__ hnew) {
    __shared__ float s_in[MB * F_IN];
    const int t = threadIdx.x;
    const int node0 = blockIdx.x * MB;

    // stage x tile (coalesced), apply inter-layer leaky_relu on the fly
    for (int i = t; i < MB * K; i += 256) {
        float v = in[(size_t)node0 * K + i];
        if (act) v = v >= 0.f ? v : 0.01f * v;
        s_in[i] = v;
    }
    // init softmax state + hnew accumulator for this layer
    if (t < MB * HEADS) {
        mx[node0 * HEADS + t]  = -INFINITY;
        dnm[node0 * HEADS + t] = 0.f;
    }
    #pragma unroll
    for (int i = 0; i < MB * HID / 256; ++i)
        hnew[(size_t)node0 * HID + i * 256 + t] = 0.f;
    __syncthreads();

    float accl[MB], accr[MB];
    const float bll = bl[t], brr = br[t];
    #pragma unroll
    for (int m = 0; m < MB; ++m) { accl[m] = bll; accr[m] = brr; }

    for (int k = 0; k < K; k += 4) {
        float wl[4], wr[4];
        #pragma unroll
        for (int u = 0; u < 4; ++u) {
            wl[u] = Wl[(size_t)(k + u) * HC + t];
            wr[u] = Wr[(size_t)(k + u) * HC + t];
        }
        #pragma unroll
        for (int m = 0; m < MB; ++m) {
            const float4 v = *(const float4*)(s_in + m * K + k);
            accl[m] = fmaf(v.x, wl[0], accl[m]);
            accl[m] = fmaf(v.y, wl[1], accl[m]);
            accl[m] = fmaf(v.z, wl[2], accl[m]);
            accl[m] = fmaf(v.w, wl[3], accl[m]);
            accr[m] = fmaf(v.x, wr[0], accr[m]);
            accr[m] = fmaf(v.y, wr[1], accr[m]);
            accr[m] = fmaf(v.z, wr[2], accr[m]);
            accr[m] = fmaf(v.w, wr[3], accr[m]);
        }
    }
    #pragma unroll
    for (int m = 0; m < MB; ++m) {
        xl[(size_t)(node0 + m) * HC + t] = accl[m];
        xr[(size_t)(node0 + m) * HC + t] = accr[m];
    }
}

// One wave (64 lanes) per edge; lane handles 4 channels (float4).
__global__ void edge_logits(const float* __restrict__ ea,
                            const int* __restrict__ src, const int* __restrict__ dst,
                            const float* __restrict__ We, const float* __restrict__ att,
                            const float* __restrict__ xl, const float* __restrict__ xr,
                            float* __restrict__ plog, float* __restrict__ mx) {
    const int wave = threadIdx.x >> 6;
    const int lane = threadIdx.x & 63;
    const int e = blockIdx.x * 4 + wave;
    if (e >= N_EDGES) return;
    const int s = src[e], d = dst[e];

    float ef[EDIM];
    #pragma unroll
    for (int j = 0; j < EDIM; ++j) ef[j] = ea[(size_t)e * EDIM + j];

    const int c0 = lane * 4;
    const float4 vxl = *(const float4*)(xl + (size_t)s * HC + c0);
    const float4 vxr = *(const float4*)(xr + (size_t)d * HC + c0);
    const float4 vat = *(const float4*)(att + c0);
    float partial = 0.f;
    #pragma unroll
    for (int u = 0; u < 4; ++u) {
        const int c = c0 + u;
        float ev = 0.f;
        #pragma unroll
        for (int j = 0; j < EDIM; ++j) ev = fmaf(ef[j], We[j * HC + c], ev);
        float m = (&vxl.x)[u] + (&vxr.x)[u] + ev;
        m = m >= 0.f ? m : 0.2f * m;
        partial = fmaf(m, (&vat.x)[u], partial);
    }
    partial += __shfl_down(partial, 8, 64);
    partial += __shfl_down(partial, 4, 64);
    partial += __shfl_down(partial, 2, 64);
    partial += __shfl_down(partial, 1, 64);
    if ((lane & 15) == 0) {
        const int hh = lane >> 4;
        plog[(size_t)e * HEADS + hh] = partial;
        atomicMaxFloat(&mx[d * HEADS + hh], partial);
    }
}

__global__ void edge_softmax_denom(const int* __restrict__ dst,
                                   float* __restrict__ plog,
                                   const float* __restrict__ mx,
                                   float* __restrict__ dnm) {
    const int i = blockIdx.x * blockDim.x + threadIdx.x;
    if (i >= N_EDGES * HEADS) return;
    const int e = i >> 2, hh = i & 3;
    const int d = dst[e];
    const float p = expf(plog[i] - mx[d * HEADS + hh]);
    plog[i] = p;
    atomicAdd(&dnm[d * HEADS + hh], p);
}

// One wave per edge; lane c in [0,64): hnew[d][c] += sum_h 0.25*alpha_h*xl[s][h*64+c]
__global__ void edge_scatter(const int* __restrict__ src, const int* __restrict__ dst,
                             const float* __restrict__ xl, const float* __restrict__ plog,
                             const float* __restrict__ dnm, float* __restrict__ hnew) {
    const int wave = threadIdx.x >> 6;
    const int lane = threadIdx.x & 63;
    const int e = blockIdx.x * 4 + wave;
    if (e >= N_EDGES) return;
    const int s = src[e], d = dst[e];
    float w[HEADS];
    #pragma unroll
    for (int hh = 0; hh < HEADS; ++hh)
        w[hh] = 0.25f * plog[(size_t)e * HEADS + hh] / (dnm[d * HEADS + hh] + 1e-16f);
    float val = 0.f;
    #pragma unroll
    for (int hh = 0; hh < HEADS; ++hh)
        val = fmaf(w[hh], xl[(size_t)s * HC + hh * HID + lane], val);
    atomicAdd(&hnew[(size_t)d * HID + lane], val);
}

__global__ void finalize(const float* __restrict__ hnew, const float* __restrict__ bias,
                         const float* __restrict__ gates, float* __restrict__ h,
                         int gated, int gate_idx) {
    const int i = blockIdx.x * blockDim.x + threadIdx.x;
    if (i >= N_NODES * HID) return;
    const int c = i & (HID - 1);
    float v = hnew[i] + bias[c];
    if (gated) {
        const float g = 1.f / (1.f + expf(-gates[gate_idx]));
        float a = h[i];
        a = a >= 0.f ? a : 0.01f * a;
        v = g * v + (1.f - g) * a;
    }
    h[i] = v;
}

extern "C" void kernel_launch(void* const* d_in, const int* in_sizes, int n_in,
                              void* d_out, int out_size, void* d_ws, size_t ws_size,
                              hipStream_t stream) {
    const float* x     = (const float*)d_in[0];
    const float* ea    = (const float*)d_in[1];
    const float* iWl   = (const float*)d_in[2];
    const float* ibl   = (const float*)d_in[3];
    const float* iWr   = (const float*)d_in[4];
    const float* ibr   = (const float*)d_in[5];
    const float* iWe   = (const float*)d_in[6];
    const float* iatt  = (const float*)d_in[7];
    const float* ibias = (const float*)d_in[8];
    const float* Wl    = (const float*)d_in[9];
    const float* bl    = (const float*)d_in[10];
    const float* Wr    = (const float*)d_in[11];
    const float* br    = (const float*)d_in[12];
    const float* We    = (const float*)d_in[13];
    const float* att   = (const float*)d_in[14];
    const float* bias  = (const float*)d_in[15];
    const float* gates = (const float*)d_in[16];
    const int*   ei    = (const int*)d_in[17];
    const int* src = ei;
    const int* dst = ei + N_EDGES;

    float* ws   = (float*)d_ws;
    float* xl   = ws;
    float* xr   = xl   + (size_t)N_NODES * HC;
    float* plog = xr   + (size_t)N_NODES * HC;
    float* mx   = plog + (size_t)N_EDGES * HEADS;
    float* dnm  = mx   + (size_t)N_NODES * HEADS;
    float* hnew = dnm  + (size_t)N_NODES * HEADS;
    float* h    = (float*)d_out;

    for (int layer = 0; layer < 3; ++layer) {
        const float* in_   = (layer == 0) ? x : h;
        const int    K     = (layer == 0) ? F_IN : HID;
        const int    act   = (layer == 0) ? 0 : 1;
        const float* wl_   = (layer == 0) ? iWl   : Wl   + (size_t)(layer - 1) * HID * HC;
        const float* bl_   = (layer == 0) ? ibl   : bl   + (size_t)(layer - 1) * HC;
        const float* wr_   = (layer == 0) ? iWr   : Wr   + (size_t)(layer - 1) * HID * HC;
        const float* br_   = (layer == 0) ? ibr   : br   + (size_t)(layer - 1) * HC;
        const float* we_   = (layer == 0) ? iWe   : We   + (size_t)(layer - 1) * EDIM * HC;
        const float* att_  = (layer == 0) ? iatt  : att  + (size_t)(layer - 1) * HC;
        const float* bias_ = (layer == 0) ? ibias : bias + (size_t)(layer - 1) * HID;

        node_transform<<<N_NODES / MB, 256, 0, stream>>>(in_, K, act, wl_, bl_, wr_, br_,
                                                         xl, xr, mx, dnm, hnew);
        edge_logits<<<N_EDGES / 4, 256, 0, stream>>>(ea, src, dst, we_, att_, xl, xr, plog, mx);
        edge_softmax_denom<<<(N_EDGES * HEADS + 255) / 256, 256, 0, stream>>>(dst, plog, mx, dnm);
        edge_scatter<<<N_EDGES / 4, 256, 0, stream>>>(src, dst, xl, plog, dnm, hnew);
        finalize<<<(N_NODES * HID + 255) / 256, 256, 0, stream>>>(hnew, bias_, gates, h,
                                                                  (layer == 0) ? 0 : 1, layer - 1);
    }
}

// Round 3
// 742.442 us; speedup vs baseline: 3.5002x; 2.7054x over previous
//
#include <hip/hip_runtime.h>
#include <math.h>

#define N_NODES 50000
#define N_EDGES 800000
#define F_IN    128
#define HID     64
#define HEADS   4
#define HC      256      // HEADS*HID
#define EDIM    9
#define MB      16       // nodes per block in node_transform
#define NSCAN   ((N_NODES + 255) / 256)   // 196

// ---------------- node transform: xl = in@Wl+bl, xr = in@Wr+br ----------------
__global__ void node_transform(const float* __restrict__ in, int K, int act,
                               const float* __restrict__ Wl, const float* __restrict__ bl,
                               const float* __restrict__ Wr, const float* __restrict__ br,
                               float* __restrict__ xl, float* __restrict__ xr) {
    __shared__ float s_in[MB * F_IN];
    const int t = threadIdx.x;
    const int node0 = blockIdx.x * MB;

    for (int i = t; i < MB * K; i += 256) {
        float v = in[(size_t)node0 * K + i];
        if (act) v = v >= 0.f ? v : 0.01f * v;   // inter-layer leaky_relu on the fly
        s_in[i] = v;
    }
    __syncthreads();

    float accl[MB], accr[MB];
    const float bll = bl[t], brr = br[t];
    #pragma unroll
    for (int m = 0; m < MB; ++m) { accl[m] = bll; accr[m] = brr; }

    for (int k = 0; k < K; k += 4) {
        float wl[4], wr[4];
        #pragma unroll
        for (int u = 0; u < 4; ++u) {
            wl[u] = Wl[(size_t)(k + u) * HC + t];
            wr[u] = Wr[(size_t)(k + u) * HC + t];
        }
        #pragma unroll
        for (int m = 0; m < MB; ++m) {
            const float4 v = *(const float4*)(s_in + m * K + k);
            accl[m] = fmaf(v.x, wl[0], accl[m]);
            accl[m] = fmaf(v.y, wl[1], accl[m]);
            accl[m] = fmaf(v.z, wl[2], accl[m]);
            accl[m] = fmaf(v.w, wl[3], accl[m]);
            accr[m] = fmaf(v.x, wr[0], accr[m]);
            accr[m] = fmaf(v.y, wr[1], accr[m]);
            accr[m] = fmaf(v.z, wr[2], accr[m]);
            accr[m] = fmaf(v.w, wr[3], accr[m]);
        }
    }
    #pragma unroll
    for (int m = 0; m < MB; ++m) {
        xl[(size_t)(node0 + m) * HC + t] = accl[m];
        xr[(size_t)(node0 + m) * HC + t] = accr[m];
    }
}

// ---------------- CSR build (once per launch; graph shared by all layers) ----------------
__global__ void zero_counts(int* __restrict__ counts, int* __restrict__ cursor) {
    const int i = blockIdx.x * blockDim.x + threadIdx.x;
    if (i < N_NODES) { counts[i] = 0; cursor[i] = 0; }
}

__global__ void count_deg(const int* __restrict__ dst, int* __restrict__ counts) {
    const int e = blockIdx.x * blockDim.x + threadIdx.x;
    if (e < N_EDGES) atomicAdd(&counts[dst[e]], 1);
}

__global__ void scanA(const int* __restrict__ counts, int* __restrict__ bsum) {
    __shared__ int s[256];
    const int t = threadIdx.x;
    const int i = blockIdx.x * 256 + t;
    s[t] = (i < N_NODES) ? counts[i] : 0;
    __syncthreads();
    for (int st = 128; st > 0; st >>= 1) {
        if (t < st) s[t] += s[t + st];
        __syncthreads();
    }
    if (t == 0) bsum[blockIdx.x] = s[0];
}

__global__ void scanB(const int* __restrict__ bsum, int* __restrict__ boff) {
    __shared__ int s[256];
    const int t = threadIdx.x;
    const int orig = (t < NSCAN) ? bsum[t] : 0;
    s[t] = orig;
    __syncthreads();
    for (int st = 1; st < 256; st <<= 1) {
        int v = (t >= st) ? s[t - st] : 0;
        __syncthreads();
        s[t] += v;
        __syncthreads();
    }
    if (t < NSCAN) boff[t] = s[t] - orig;   // exclusive
}

__global__ void scanC(const int* __restrict__ counts, const int* __restrict__ boff,
                      int* __restrict__ offs) {
    __shared__ int s[256];
    const int t = threadIdx.x;
    const int i = blockIdx.x * 256 + t;
    const int orig = (i < N_NODES) ? counts[i] : 0;
    s[t] = orig;
    __syncthreads();
    for (int st = 1; st < 256; st <<= 1) {
        int v = (t >= st) ? s[t - st] : 0;
        __syncthreads();
        s[t] += v;
        __syncthreads();
    }
    if (i < N_NODES) offs[i] = boff[blockIdx.x] + s[t] - orig;  // exclusive
    if (i == 0) offs[N_NODES] = N_EDGES;
}

__global__ void fill_csr(const int* __restrict__ src, const int* __restrict__ dst,
                         const int* __restrict__ offs, int* __restrict__ cursor,
                         int* __restrict__ srcp, int* __restrict__ perm) {
    const int e = blockIdx.x * blockDim.x + threadIdx.x;
    if (e >= N_EDGES) return;
    const int d = dst[e];
    const int pos = offs[d] + atomicAdd(&cursor[d], 1);
    srcp[pos] = src[e];
    perm[pos] = e;
}

// ---------------- fused per-dst-node edge kernel ----------------
// One wave (64-thread block) per destination node. Online softmax over in-edges.
// lane holds channels c0..c0+3 of head hh = lane>>4.
__global__ __launch_bounds__(64) void fused_edge(
        const float* __restrict__ xl, const float* __restrict__ xr,
        const float* __restrict__ ea,
        const int* __restrict__ offs, const int* __restrict__ srcp,
        const int* __restrict__ perm,
        const float* __restrict__ We, const float* __restrict__ att,
        const float* __restrict__ bias, const float* __restrict__ gates,
        float* __restrict__ h, int layer) {
    const int d = blockIdx.x;
    const int lane = threadIdx.x;
    const int c0 = lane * 4;

    const float4 vxr  = *(const float4*)(xr + (size_t)d * HC + c0);
    const float4 watt = *(const float4*)(att + c0);
    float4 wWe[EDIM];
    #pragma unroll
    for (int j = 0; j < EDIM; ++j) wWe[j] = *(const float4*)(We + j * HC + c0);

    float m = -INFINITY, den = 0.f;
    float4 acc = {0.f, 0.f, 0.f, 0.f};

    const int jb = offs[d], je = offs[d + 1];
    for (int j = jb; j < je; ++j) {
        const int s  = srcp[j];
        const int pe = perm[j];
        const float4 vxl = *(const float4*)(xl + (size_t)s * HC + c0);
        float4 t4;
        t4.x = vxl.x + vxr.x;
        t4.y = vxl.y + vxr.y;
        t4.z = vxl.z + vxr.z;
        t4.w = vxl.w + vxr.w;
        #pragma unroll
        for (int jj = 0; jj < EDIM; ++jj) {
            const float ef = ea[(size_t)pe * EDIM + jj];   // wave-uniform
            t4.x = fmaf(ef, wWe[jj].x, t4.x);
            t4.y = fmaf(ef, wWe[jj].y, t4.y);
            t4.z = fmaf(ef, wWe[jj].z, t4.z);
            t4.w = fmaf(ef, wWe[jj].w, t4.w);
        }
        t4.x = t4.x >= 0.f ? t4.x : 0.2f * t4.x;
        t4.y = t4.y >= 0.f ? t4.y : 0.2f * t4.y;
        t4.z = t4.z >= 0.f ? t4.z : 0.2f * t4.z;
        t4.w = t4.w >= 0.f ? t4.w : 0.2f * t4.w;
        float l = fmaf(t4.x, watt.x, fmaf(t4.y, watt.y, fmaf(t4.z, watt.z, t4.w * watt.w)));
        // sum over the 16 lanes of this head group
        l += __shfl_xor(l, 1, 64);
        l += __shfl_xor(l, 2, 64);
        l += __shfl_xor(l, 4, 64);
        l += __shfl_xor(l, 8, 64);
        // online softmax update
        const float nm = fmaxf(m, l);
        const float sc = __expf(m - nm);   // 0 on first edge (m = -inf)
        const float p  = __expf(l - nm);
        den = den * sc + p;
        acc.x = fmaf(acc.x, sc, p * vxl.x);
        acc.y = fmaf(acc.y, sc, p * vxl.y);
        acc.z = fmaf(acc.z, sc, p * vxl.z);
        acc.w = fmaf(acc.w, sc, p * vxl.w);
        m = nm;
    }

    const float inv = 1.f / (den + 1e-16f);
    float4 v;
    v.x = acc.x * inv; v.y = acc.y * inv; v.z = acc.z * inv; v.w = acc.w * inv;
    // head mean: sum across the 4 head groups (lane bits 4,5)
    v.x += __shfl_xor(v.x, 16, 64);  v.x += __shfl_xor(v.x, 32, 64);
    v.y += __shfl_xor(v.y, 16, 64);  v.y += __shfl_xor(v.y, 32, 64);
    v.z += __shfl_xor(v.z, 16, 64);  v.z += __shfl_xor(v.z, 32, 64);
    v.w += __shfl_xor(v.w, 16, 64);  v.w += __shfl_xor(v.w, 32, 64);

    if (lane < 16) {
        const int c = lane * 4;
        float4 outv;
        outv.x = fmaf(0.25f, v.x, bias[c + 0]);
        outv.y = fmaf(0.25f, v.y, bias[c + 1]);
        outv.z = fmaf(0.25f, v.z, bias[c + 2]);
        outv.w = fmaf(0.25f, v.w, bias[c + 3]);
        if (layer > 0) {
            const float g = 1.f / (1.f + __expf(-gates[layer - 1]));
            float4 pv = *(const float4*)(h + (size_t)d * HID + c);
            pv.x = pv.x >= 0.f ? pv.x : 0.01f * pv.x;
            pv.y = pv.y >= 0.f ? pv.y : 0.01f * pv.y;
            pv.z = pv.z >= 0.f ? pv.z : 0.01f * pv.z;
            pv.w = pv.w >= 0.f ? pv.w : 0.01f * pv.w;
            outv.x = g * outv.x + (1.f - g) * pv.x;
            outv.y = g * outv.y + (1.f - g) * pv.y;
            outv.z = g * outv.z + (1.f - g) * pv.z;
            outv.w = g * outv.w + (1.f - g) * pv.w;
        }
        *(float4*)(h + (size_t)d * HID + c) = outv;
    }
}

extern "C" void kernel_launch(void* const* d_in, const int* in_sizes, int n_in,
                              void* d_out, int out_size, void* d_ws, size_t ws_size,
                              hipStream_t stream) {
    const float* x     = (const float*)d_in[0];
    const float* ea    = (const float*)d_in[1];
    const float* iWl   = (const float*)d_in[2];
    const float* ibl   = (const float*)d_in[3];
    const float* iWr   = (const float*)d_in[4];
    const float* ibr   = (const float*)d_in[5];
    const float* iWe   = (const float*)d_in[6];
    const float* iatt  = (const float*)d_in[7];
    const float* ibias = (const float*)d_in[8];
    const float* Wl    = (const float*)d_in[9];
    const float* bl    = (const float*)d_in[10];
    const float* Wr    = (const float*)d_in[11];
    const float* br    = (const float*)d_in[12];
    const float* We    = (const float*)d_in[13];
    const float* att   = (const float*)d_in[14];
    const float* bias  = (const float*)d_in[15];
    const float* gates = (const float*)d_in[16];
    const int*   ei    = (const int*)d_in[17];
    const int* src = ei;
    const int* dst = ei + N_EDGES;

    float* ws = (float*)d_ws;
    float* xl = ws;                                   // 50000*256
    float* xr = xl + (size_t)N_NODES * HC;            // 50000*256
    int* ibase  = (int*)(xr + (size_t)N_NODES * HC);
    int* counts = ibase;                              // 50000
    int* cursor = counts + N_NODES;                   // 50000
    int* offs   = cursor + N_NODES;                   // 50001
    int* bsum   = offs + N_NODES + 1;                 // 256
    int* boff   = bsum + 256;                         // 256
    int* srcp   = boff + 256;                         // 800000
    int* perm   = srcp + N_EDGES;                     // 800000
    float* h    = (float*)d_out;

    // CSR build (graph identical for all 3 layers)
    zero_counts<<<(N_NODES + 255) / 256, 256, 0, stream>>>(counts, cursor);
    count_deg<<<(N_EDGES + 255) / 256, 256, 0, stream>>>(dst, counts);
    scanA<<<NSCAN, 256, 0, stream>>>(counts, bsum);
    scanB<<<1, 256, 0, stream>>>(bsum, boff);
    scanC<<<NSCAN, 256, 0, stream>>>(counts, boff, offs);
    fill_csr<<<(N_EDGES + 255) / 256, 256, 0, stream>>>(src, dst, offs, cursor, srcp, perm);

    for (int layer = 0; layer < 3; ++layer) {
        const float* in_   = (layer == 0) ? x : h;
        const int    K     = (layer == 0) ? F_IN : HID;
        const int    act   = (layer == 0) ? 0 : 1;
        const float* wl_   = (layer == 0) ? iWl   : Wl   + (size_t)(layer - 1) * HID * HC;
        const float* bl_   = (layer == 0) ? ibl   : bl   + (size_t)(layer - 1) * HC;
        const float* wr_   = (layer == 0) ? iWr   : Wr   + (size_t)(layer - 1) * HID * HC;
        const float* br_   = (layer == 0) ? ibr   : br   + (size_t)(layer - 1) * HC;
        const float* we_   = (layer == 0) ? iWe   : We   + (size_t)(layer - 1) * EDIM * HC;
        const float* att_  = (layer == 0) ? iatt  : att  + (size_t)(layer - 1) * HC;
        const float* bias_ = (layer == 0) ? ibias : bias + (size_t)(layer - 1) * HID;

        node_transform<<<N_NODES / MB, 256, 0, stream>>>(in_, K, act, wl_, bl_, wr_, br_, xl, xr);
        fused_edge<<<N_NODES, 64, 0, stream>>>(xl, xr, ea, offs, srcp, perm,
                                               we_, att_, bias_, gates, h, layer);
    }
}

// Round 4
// 741.521 us; speedup vs baseline: 3.5046x; 1.0012x over previous
//
#include <hip/hip_runtime.h>
#include <math.h>

#define N_NODES 50000
#define N_EDGES 800000
#define F_IN    128
#define HID     64
#define HEADS   4
#define HC      256      // HEADS*HID
#define EDIM    9
#define MB      16       // nodes per block in node_transform
#define NSCAN   ((N_NODES + 255) / 256)   // 196

// ---------------- weight transpose: Wt4[kk*256+t] = {W[4kk..4kk+3][t]} ----------------
__global__ void transpose_w(const float* __restrict__ W, int K4, float4* __restrict__ Wt) {
    const int i = blockIdx.x * 256 + threadIdx.x;   // i = kk*256 + t
    if (i >= K4 * 256) return;
    const int t = i & 255, kk = i >> 8;
    float4 v;
    v.x = W[(size_t)(4 * kk + 0) * HC + t];
    v.y = W[(size_t)(4 * kk + 1) * HC + t];
    v.z = W[(size_t)(4 * kk + 2) * HC + t];
    v.w = W[(size_t)(4 * kk + 3) * HC + t];
    Wt[i] = v;
}

// ---------------- node transform: xl = in@Wl+bl, xr = in@Wr+br ----------------
template<int K>
__global__ __launch_bounds__(256) void node_transform_t(
        const float* __restrict__ in, int act,
        const float4* __restrict__ Wlt, const float* __restrict__ bl,
        const float4* __restrict__ Wrt, const float* __restrict__ br,
        float* __restrict__ xl, float* __restrict__ xr) {
    __shared__ float s_in[MB * K];
    const int t = threadIdx.x;
    const int node0 = blockIdx.x * MB;

    for (int i = t; i < MB * K; i += 256) {
        float v = in[(size_t)node0 * K + i];
        if (act) v = fmaxf(v, 0.01f * v);   // inter-layer leaky_relu
        s_in[i] = v;
    }
    __syncthreads();

    float accl[MB], accr[MB];
    const float bll = bl[t], brr = br[t];
    #pragma unroll
    for (int m = 0; m < MB; ++m) { accl[m] = bll; accr[m] = brr; }

    #pragma unroll 2
    for (int kk = 0; kk < K / 4; ++kk) {
        const float4 wl = Wlt[kk * 256 + t];
        const float4 wr = Wrt[kk * 256 + t];
        #pragma unroll
        for (int m = 0; m < MB; ++m) {
            const float4 v = *(const float4*)(s_in + m * K + kk * 4);
            accl[m] = fmaf(v.x, wl.x, accl[m]);
            accl[m] = fmaf(v.y, wl.y, accl[m]);
            accl[m] = fmaf(v.z, wl.z, accl[m]);
            accl[m] = fmaf(v.w, wl.w, accl[m]);
            accr[m] = fmaf(v.x, wr.x, accr[m]);
            accr[m] = fmaf(v.y, wr.y, accr[m]);
            accr[m] = fmaf(v.z, wr.z, accr[m]);
            accr[m] = fmaf(v.w, wr.w, accr[m]);
        }
    }
    #pragma unroll
    for (int m = 0; m < MB; ++m) {
        xl[(size_t)(node0 + m) * HC + t] = accl[m];
        xr[(size_t)(node0 + m) * HC + t] = accr[m];
    }
}

// ---------------- CSR build (once per launch) ----------------
__global__ void zero_counts(int* __restrict__ counts, int* __restrict__ cursor) {
    const int i = blockIdx.x * blockDim.x + threadIdx.x;
    if (i < N_NODES) { counts[i] = 0; cursor[i] = 0; }
}

__global__ void count_deg(const int* __restrict__ dst, int* __restrict__ counts) {
    const int e = blockIdx.x * blockDim.x + threadIdx.x;
    if (e < N_EDGES) atomicAdd(&counts[dst[e]], 1);
}

__global__ void scanA(const int* __restrict__ counts, int* __restrict__ bsum) {
    __shared__ int s[256];
    const int t = threadIdx.x;
    const int i = blockIdx.x * 256 + t;
    s[t] = (i < N_NODES) ? counts[i] : 0;
    __syncthreads();
    for (int st = 128; st > 0; st >>= 1) {
        if (t < st) s[t] += s[t + st];
        __syncthreads();
    }
    if (t == 0) bsum[blockIdx.x] = s[0];
}

__global__ void scanB(const int* __restrict__ bsum, int* __restrict__ boff) {
    __shared__ int s[256];
    const int t = threadIdx.x;
    const int orig = (t < NSCAN) ? bsum[t] : 0;
    s[t] = orig;
    __syncthreads();
    for (int st = 1; st < 256; st <<= 1) {
        int v = (t >= st) ? s[t - st] : 0;
        __syncthreads();
        s[t] += v;
        __syncthreads();
    }
    if (t < NSCAN) boff[t] = s[t] - orig;   // exclusive
}

__global__ void scanC(const int* __restrict__ counts, const int* __restrict__ boff,
                      int* __restrict__ offs) {
    __shared__ int s[256];
    const int t = threadIdx.x;
    const int i = blockIdx.x * 256 + t;
    const int orig = (i < N_NODES) ? counts[i] : 0;
    s[t] = orig;
    __syncthreads();
    for (int st = 1; st < 256; st <<= 1) {
        int v = (t >= st) ? s[t - st] : 0;
        __syncthreads();
        s[t] += v;
        __syncthreads();
    }
    if (i < N_NODES) offs[i] = boff[blockIdx.x] + s[t] - orig;  // exclusive
    if (i == 0) offs[N_NODES] = N_EDGES;
}

__global__ void fill_csr(const int* __restrict__ src, const int* __restrict__ dst,
                         const int* __restrict__ offs, int* __restrict__ cursor,
                         int* __restrict__ srcp, int* __restrict__ perm) {
    const int e = blockIdx.x * blockDim.x + threadIdx.x;
    if (e >= N_EDGES) return;
    const int d = dst[e];
    const int pos = offs[d] + atomicAdd(&cursor[d], 1);
    srcp[pos] = src[e];
    perm[pos] = e;
}

// permute edge_attr into CSR order: eap[j][:] = ea[perm[j]][:]
__global__ void permute_ea(const float* __restrict__ ea, const int* __restrict__ perm,
                           float* __restrict__ eap) {
    const int j = blockIdx.x * blockDim.x + threadIdx.x;
    if (j >= N_EDGES) return;
    const int e = perm[j];
    #pragma unroll
    for (int u = 0; u < EDIM; ++u)
        eap[(size_t)j * EDIM + u] = ea[(size_t)e * EDIM + u];
}

// ---------------- fused per-dst-node edge kernel ----------------
// One wave per destination node; online softmax over in-edges; 2-deep pipeline.
template<int PERMUTED>
__global__ __launch_bounds__(64) void fused_edge(
        const float* __restrict__ xl, const float* __restrict__ xr,
        const float* __restrict__ eap, const float* __restrict__ ea,
        const int* __restrict__ perm,
        const int* __restrict__ offs, const int* __restrict__ srcp,
        const float* __restrict__ We, const float* __restrict__ att,
        const float* __restrict__ bias, const float* __restrict__ gates,
        float* __restrict__ h, int layer) {
    const int d = blockIdx.x;
    const int lane = threadIdx.x;
    const int c0 = lane * 4;

    const float4 vxr  = *(const float4*)(xr + (size_t)d * HC + c0);
    const float4 watt = *(const float4*)(att + c0);
    float4 wWe[EDIM];
    #pragma unroll
    for (int u = 0; u < EDIM; ++u) wWe[u] = *(const float4*)(We + u * HC + c0);

    float m = -INFINITY, den = 0.f;
    float4 acc = {0.f, 0.f, 0.f, 0.f};

    const int jb = offs[d], je = offs[d + 1];

    float4 aA, aB;
    float eA[EDIM], eB[EDIM];

    auto loadE = [&](int j, float4& a, float (&e)[EDIM]) {
        const int s = srcp[j];
        const float* ep = PERMUTED ? (eap + (size_t)j * EDIM)
                                   : (ea + (size_t)perm[j] * EDIM);
        a = *(const float4*)(xl + (size_t)s * HC + c0);
        #pragma unroll
        for (int u = 0; u < EDIM; ++u) e[u] = ep[u];
    };

    auto compute = [&](const float4& a, const float (&e)[EDIM]) {
        float4 t;
        t.x = a.x + vxr.x; t.y = a.y + vxr.y; t.z = a.z + vxr.z; t.w = a.w + vxr.w;
        #pragma unroll
        for (int u = 0; u < EDIM; ++u) {
            t.x = fmaf(e[u], wWe[u].x, t.x);
            t.y = fmaf(e[u], wWe[u].y, t.y);
            t.z = fmaf(e[u], wWe[u].z, t.z);
            t.w = fmaf(e[u], wWe[u].w, t.w);
        }
        t.x = fmaxf(t.x, 0.2f * t.x);
        t.y = fmaxf(t.y, 0.2f * t.y);
        t.z = fmaxf(t.z, 0.2f * t.z);
        t.w = fmaxf(t.w, 0.2f * t.w);
        float l = fmaf(t.x, watt.x, fmaf(t.y, watt.y, fmaf(t.z, watt.z, t.w * watt.w)));
        l += __shfl_xor(l, 1, 64);
        l += __shfl_xor(l, 2, 64);
        l += __shfl_xor(l, 4, 64);
        l += __shfl_xor(l, 8, 64);
        if (__ballot(l > m)) {          // wave-uniform: some head has a new max
            const float nm = fmaxf(m, l);
            const float sc = __expf(m - nm);
            const float p  = __expf(l - nm);
            den = fmaf(den, sc, p);
            acc.x = fmaf(acc.x, sc, p * a.x);
            acc.y = fmaf(acc.y, sc, p * a.y);
            acc.z = fmaf(acc.z, sc, p * a.z);
            acc.w = fmaf(acc.w, sc, p * a.w);
            m = nm;
        } else {                        // defer path: max unchanged, no rescale
            const float p = __expf(l - m);
            den += p;
            acc.x = fmaf(p, a.x, acc.x);
            acc.y = fmaf(p, a.y, acc.y);
            acc.z = fmaf(p, a.z, acc.z);
            acc.w = fmaf(p, a.w, acc.w);
        }
    };

    int j = jb;
    if (j < je) loadE(j, aA, eA);
    while (j + 1 < je) {
        loadE(j + 1, aB, eB);
        compute(aA, eA);
        if (j + 2 < je) {
            loadE(j + 2, aA, eA);
            compute(aB, eB);
        } else {
            compute(aB, eB);
        }
        j += 2;
    }
    if (j < je) compute(aA, eA);

    const float inv = 1.f / (den + 1e-16f);
    float4 v;
    v.x = acc.x * inv; v.y = acc.y * inv; v.z = acc.z * inv; v.w = acc.w * inv;
    // head mean: sum across the 4 head groups (lane bits 4,5)
    v.x += __shfl_xor(v.x, 16, 64);  v.x += __shfl_xor(v.x, 32, 64);
    v.y += __shfl_xor(v.y, 16, 64);  v.y += __shfl_xor(v.y, 32, 64);
    v.z += __shfl_xor(v.z, 16, 64);  v.z += __shfl_xor(v.z, 32, 64);
    v.w += __shfl_xor(v.w, 16, 64);  v.w += __shfl_xor(v.w, 32, 64);

    if (lane < 16) {
        const int c = lane * 4;
        float4 outv;
        outv.x = fmaf(0.25f, v.x, bias[c + 0]);
        outv.y = fmaf(0.25f, v.y, bias[c + 1]);
        outv.z = fmaf(0.25f, v.z, bias[c + 2]);
        outv.w = fmaf(0.25f, v.w, bias[c + 3]);
        if (layer > 0) {
            const float g = 1.f / (1.f + __expf(-gates[layer - 1]));
            float4 pv = *(const float4*)(h + (size_t)d * HID + c);
            pv.x = fmaxf(pv.x, 0.01f * pv.x);
            pv.y = fmaxf(pv.y, 0.01f * pv.y);
            pv.z = fmaxf(pv.z, 0.01f * pv.z);
            pv.w = fmaxf(pv.w, 0.01f * pv.w);
            outv.x = g * outv.x + (1.f - g) * pv.x;
            outv.y = g * outv.y + (1.f - g) * pv.y;
            outv.z = g * outv.z + (1.f - g) * pv.z;
            outv.w = g * outv.w + (1.f - g) * pv.w;
        }
        *(float4*)(h + (size_t)d * HID + c) = outv;
    }
}

extern "C" void kernel_launch(void* const* d_in, const int* in_sizes, int n_in,
                              void* d_out, int out_size, void* d_ws, size_t ws_size,
                              hipStream_t stream) {
    const float* x     = (const float*)d_in[0];
    const float* ea    = (const float*)d_in[1];
    const float* iWl   = (const float*)d_in[2];
    const float* ibl   = (const float*)d_in[3];
    const float* iWr   = (const float*)d_in[4];
    const float* ibr   = (const float*)d_in[5];
    const float* iWe   = (const float*)d_in[6];
    const float* iatt  = (const float*)d_in[7];
    const float* ibias = (const float*)d_in[8];
    const float* Wl    = (const float*)d_in[9];
    const float* bl    = (const float*)d_in[10];
    const float* Wr    = (const float*)d_in[11];
    const float* br    = (const float*)d_in[12];
    const float* We    = (const float*)d_in[13];
    const float* att   = (const float*)d_in[14];
    const float* bias  = (const float*)d_in[15];
    const float* gates = (const float*)d_in[16];
    const int*   ei    = (const int*)d_in[17];
    const int* src = ei;
    const int* dst = ei + N_EDGES;

    float* ws = (float*)d_ws;
    float*  xl   = ws;                                 // 12.8M floats
    float*  xr   = xl + (size_t)N_NODES * HC;          // 12.8M
    float4* wlt  = (float4*)(xr + (size_t)N_NODES * HC);  // 32768 float4
    float4* wrt  = wlt + 32768;                        // 32768 float4
    float*  eap  = (float*)(wrt + 32768);              // 7.2M floats (optional)
    int* ibase  = (int*)(eap + (size_t)N_EDGES * EDIM);
    int* counts = ibase;                               // 50000
    int* cursor = counts + N_NODES;                    // 50000
    int* offs   = cursor + N_NODES;                    // 50001
    int* bsum   = offs + N_NODES + 1;                  // 256
    int* boff   = bsum + 256;                          // 256
    int* srcp   = boff + 256;                          // 800000
    int* perm   = srcp + N_EDGES;                      // 800000
    float* h    = (float*)d_out;

    const size_t need = (size_t)((char*)(perm + N_EDGES) - (char*)d_ws);
    const int permuted = (ws_size >= need) ? 1 : 0;

    // CSR build (graph identical for all 3 layers)
    zero_counts<<<(N_NODES + 255) / 256, 256, 0, stream>>>(counts, cursor);
    count_deg<<<(N_EDGES + 255) / 256, 256, 0, stream>>>(dst, counts);
    scanA<<<NSCAN, 256, 0, stream>>>(counts, bsum);
    scanB<<<1, 256, 0, stream>>>(bsum, boff);
    scanC<<<NSCAN, 256, 0, stream>>>(counts, boff, offs);
    fill_csr<<<(N_EDGES + 255) / 256, 256, 0, stream>>>(src, dst, offs, cursor, srcp, perm);
    if (permuted)
        permute_ea<<<(N_EDGES + 255) / 256, 256, 0, stream>>>(ea, perm, eap);

    for (int layer = 0; layer < 3; ++layer) {
        const float* in_   = (layer == 0) ? x : h;
        const int    K     = (layer == 0) ? F_IN : HID;
        const int    act   = (layer == 0) ? 0 : 1;
        const float* wl_   = (layer == 0) ? iWl   : Wl   + (size_t)(layer - 1) * HID * HC;
        const float* bl_   = (layer == 0) ? ibl   : bl   + (size_t)(layer - 1) * HC;
        const float* wr_   = (layer == 0) ? iWr   : Wr   + (size_t)(layer - 1) * HID * HC;
        const float* br_   = (layer == 0) ? ibr   : br   + (size_t)(layer - 1) * HC;
        const float* we_   = (layer == 0) ? iWe   : We   + (size_t)(layer - 1) * EDIM * HC;
        const float* att_  = (layer == 0) ? iatt  : att  + (size_t)(layer - 1) * HC;
        const float* bias_ = (layer == 0) ? ibias : bias + (size_t)(layer - 1) * HID;

        transpose_w<<<K / 4, 256, 0, stream>>>(wl_, K / 4, wlt);
        transpose_w<<<K / 4, 256, 0, stream>>>(wr_, K / 4, wrt);
        if (K == F_IN)
            node_transform_t<F_IN><<<N_NODES / MB, 256, 0, stream>>>(in_, act, wlt, bl_, wrt, br_, xl, xr);
        else
            node_transform_t<HID><<<N_NODES / MB, 256, 0, stream>>>(in_, act, wlt, bl_, wrt, br_, xl, xr);

        if (permuted)
            fused_edge<1><<<N_NODES, 64, 0, stream>>>(xl, xr, eap, ea, perm, offs, srcp,
                                                      we_, att_, bias_, gates, h, layer);
        else
            fused_edge<0><<<N_NODES, 64, 0, stream>>>(xl, xr, eap, ea, perm, offs, srcp,
                                                      we_, att_, bias_, gates, h, layer);
    }
}